// Round 1
// baseline (135.564 us; speedup 1.0000x reference)
//
#include <hip/hip_runtime.h>
#include <stdint.h>

#define Hs 96
#define Ws 96
#define HW 9216
#define TILE 128
#define WLDS 584       // padded weight row length in halfs (576 + 8)
#define WROWB 1168     // bytes per padded weight row

typedef _Float16 h2 __attribute__((ext_vector_type(2)));
typedef _Float16 f16x8 __attribute__((ext_vector_type(8)));
typedef float f32x4 __attribute__((ext_vector_type(4)));

// ---------------- kernel 1: NCHW fp32 -> NHWC fp16 ----------------
__global__ __launch_bounds__(256) void k_transpose(const float* __restrict__ in,
                                                   _Float16* __restrict__ cl) {
  __shared__ _Float16 lt[32 * 68];  // [x:32][c:64 pad 68]
  int tid = threadIdx.x;
  int blk = blockIdx.x;
  int xt = blk % 3;
  int r = blk / 3;
  int y = r % Hs;
  int b = r / Hs;
  int x0 = xt * 32;
  {
    int xx = tid & 31, cc = tid >> 5;  // cc 0..7
    const float* src = in + (size_t)b * 64 * HW + y * Ws + x0 + xx;
#pragma unroll
    for (int i = 0; i < 8; ++i) {
      int c = cc * 8 + i;
      lt[xx * 68 + c] = (_Float16)src[(size_t)c * HW];
    }
  }
  __syncthreads();
  {
    int c4 = tid & 15, pg = tid >> 4;  // pg 0..15
    _Float16* dst = cl + ((size_t)(b * Hs + y) * Ws + x0) * 64 + c4 * 4;
#pragma unroll
    for (int i = 0; i < 2; ++i) {
      int x = pg * 2 + i;
      *(uint2*)(dst + (size_t)x * 64) = *(const uint2*)(lt + x * 68 + c4 * 4);
    }
  }
}

// ---------------- kernel 2: weight fp32 [O][C][9] -> fp16 [O][tap*64+c] -----
__global__ __launch_bounds__(576) void k_wconv(const float* __restrict__ w,
                                               _Float16* __restrict__ wbf) {
  int o = blockIdx.x;    // 64
  int r = threadIdx.x;   // 576
  int tap = r >> 6, c = r & 63;
  wbf[o * 576 + r] = (_Float16)w[(o * 64 + c) * 9 + tap];
}

// ---------------- kernel 3: fused sampling + implicit GEMM ----------------
__device__ inline unsigned pk2(float f) {
  _Float16 h = (_Float16)f;
  unsigned short us = __builtin_bit_cast(unsigned short, h);
  return (unsigned)us * 0x10001u;  // duplicate into both halves
}

__global__ __launch_bounds__(512) void k_main(
    const _Float16* __restrict__ incl, const float* __restrict__ off,
    const float* __restrict__ msk, const _Float16* __restrict__ wbf,
    const float* __restrict__ bias, float* __restrict__ out) {
  __shared__ _Float16 wlds[64 * WLDS];   // 74,752 B
  __shared__ int4 preA[9 * TILE];        // 18,432 B  corner byte addresses
  __shared__ uint4 preW[9 * TILE];       // 18,432 B  packed-h2 bilinear weights

  int tid = threadIdx.x;
  int blk = blockIdx.x;
  int b = blk & 7;              // XCD swizzle: image b pinned to XCD b
  int q0 = (blk >> 3) * TILE;   // pixel tile base

  // phase 0: weight -> LDS (row-padded)
  {
    int o = tid >> 3, seg = tid & 7;
    const uint4* s = (const uint4*)((const char*)wbf + o * 1152 + seg * 144);
    uint4* d = (uint4*)((char*)wlds + o * WROWB + seg * 144);
#pragma unroll
    for (int i = 0; i < 9; ++i) d[i] = s[i];
  }

  // phase 1: per-(pixel,tap) corner addresses + validity/mask-folded weights
  for (int i = tid; i < 9 * TILE; i += 512) {
    int t = i >> 7, p = i & 127;
    int q = q0 + p;
    int qy = q / 96, qx = q - qy * 96;
    int ty = t / 3, tx = t - ty * 3;
    float dy = off[(size_t)(b * 18 + 2 * t) * HW + q];
    float dx = off[(size_t)(b * 18 + 2 * t + 1) * HW + q];
    float mv = msk[(size_t)(b * 9 + t) * HW + q];
    float yf = (float)(qy - 1 + ty) + dy;
    float xf = (float)(qx - 1 + tx) + dx;
    float y0f = floorf(yf), x0f = floorf(xf);
    float wy = yf - y0f, wx = xf - x0f;
    int y0 = (int)y0f, x0i = (int)x0f;
    int y1 = y0 + 1, x1 = x0i + 1;
    bool yv0 = (y0 >= 0) && (y0 < Hs);
    bool yv1 = (y1 >= 0) && (y1 < Hs);
    bool xv0 = (x0i >= 0) && (x0i < Ws);
    bool xv1 = (x1 >= 0) && (x1 < Ws);
    int y0c = min(max(y0, 0), Hs - 1), y1c = min(max(y1, 0), Hs - 1);
    int x0c = min(max(x0i, 0), Ws - 1), x1c = min(max(x1, 0), Ws - 1);
    int rb = b * HW;
    int4 a;
    a.x = (rb + y0c * 96 + x0c) * 128;   // byte offsets into fp16 NHWC input
    a.y = (rb + y0c * 96 + x1c) * 128;
    a.z = (rb + y1c * 96 + x0c) * 128;
    a.w = (rb + y1c * 96 + x1c) * 128;
    float omy = 1.f - wy, omx = 1.f - wx;
    uint4 pw;
    pw.x = pk2(omy * omx * mv * ((yv0 && xv0) ? 1.f : 0.f));
    pw.y = pk2(omy * wx  * mv * ((yv0 && xv1) ? 1.f : 0.f));
    pw.z = pk2(wy  * omx * mv * ((yv1 && xv0) ? 1.f : 0.f));
    pw.w = pk2(wy  * wx  * mv * ((yv1 && xv1) ? 1.f : 0.f));
    preA[i] = a;
    preW[i] = pw;
  }
  __syncthreads();

  // phase 2: gather + packed-fp16 bilinear + MFMA
  int lane = tid & 63;
  int wid = tid >> 6;          // 0..7, 16 pixels per wave
  int n = lane & 15;           // pixel-in-16 (MFMA n / A-row m)
  int quad16 = (lane >> 4) * 16;
  int p = wid * 16 + n;        // pixel within tile
  const char* inb = (const char*)incl;
  const char* wb = (const char*)wlds + n * WROWB + quad16;

  f32x4 acc[4];
#pragma unroll
  for (int mt = 0; mt < 4; ++mt) {
    f32x4 z = {0.f, 0.f, 0.f, 0.f};
    acc[mt] = z;
  }

  for (int tap = 0; tap < 9; ++tap) {
    int4 ga = preA[tap * TILE + p];
    uint4 gw = preW[tap * TILE + p];
    h2 w00 = __builtin_bit_cast(h2, gw.x);
    h2 w01 = __builtin_bit_cast(h2, gw.y);
    h2 w10 = __builtin_bit_cast(h2, gw.z);
    h2 w11 = __builtin_bit_cast(h2, gw.w);
#pragma unroll
    for (int half = 0; half < 2; ++half) {
      int co = half * 64 + quad16;  // byte offset within this pixel's 128B
      uint4 g00 = *(const uint4*)(inb + ga.x + co);
      uint4 g01 = *(const uint4*)(inb + ga.y + co);
      uint4 g10 = *(const uint4*)(inb + ga.z + co);
      uint4 g11 = *(const uint4*)(inb + ga.w + co);
      union { unsigned u[4]; f16x8 v; } bf;
      bf.u[0] = __builtin_bit_cast(unsigned,
          (h2)(w00 * __builtin_bit_cast(h2, g00.x) + w01 * __builtin_bit_cast(h2, g01.x) +
               w10 * __builtin_bit_cast(h2, g10.x) + w11 * __builtin_bit_cast(h2, g11.x)));
      bf.u[1] = __builtin_bit_cast(unsigned,
          (h2)(w00 * __builtin_bit_cast(h2, g00.y) + w01 * __builtin_bit_cast(h2, g01.y) +
               w10 * __builtin_bit_cast(h2, g10.y) + w11 * __builtin_bit_cast(h2, g11.y)));
      bf.u[2] = __builtin_bit_cast(unsigned,
          (h2)(w00 * __builtin_bit_cast(h2, g00.z) + w01 * __builtin_bit_cast(h2, g01.z) +
               w10 * __builtin_bit_cast(h2, g10.z) + w11 * __builtin_bit_cast(h2, g11.z)));
      bf.u[3] = __builtin_bit_cast(unsigned,
          (h2)(w00 * __builtin_bit_cast(h2, g00.w) + w01 * __builtin_bit_cast(h2, g01.w) +
               w10 * __builtin_bit_cast(h2, g10.w) + w11 * __builtin_bit_cast(h2, g11.w)));
      const char* wrow = wb + tap * 128 + half * 64;
#pragma unroll
      for (int mt = 0; mt < 4; ++mt) {
        f16x8 af = *(const f16x8*)(wrow + mt * (16 * WROWB));
        acc[mt] = __builtin_amdgcn_mfma_f32_16x16x32_f16(af, bf.v, acc[mt], 0, 0, 0);
      }
    }
  }

  // epilogue: D row = quad*4 + reg, col = n
  int pix = q0 + p;
  float* op = out + (size_t)b * 64 * HW + pix;
  int mrow = quad16 >> 2;  // quad*4
#pragma unroll
  for (int mt = 0; mt < 4; ++mt) {
#pragma unroll
    for (int r = 0; r < 4; ++r) {
      int m = mt * 16 + mrow + r;
      op[(size_t)m * HW] = acc[mt][r] + bias[m];
    }
  }
}

extern "C" void kernel_launch(void* const* d_in, const int* in_sizes, int n_in,
                              void* d_out, int out_size, void* d_ws, size_t ws_size,
                              hipStream_t stream) {
  const float* input = (const float*)d_in[0];
  const float* offset = (const float*)d_in[1];
  const float* mask = (const float*)d_in[2];
  const float* weight = (const float*)d_in[3];
  const float* bias = (const float*)d_in[4];
  float* out = (float*)d_out;

  _Float16* incl = (_Float16*)d_ws;                            // 9,437,184 B
  _Float16* wbf = (_Float16*)((char*)d_ws + 9437184);          // 73,728 B

  k_transpose<<<dim3(2304), dim3(256), 0, stream>>>(input, incl);
  k_wconv<<<dim3(64), dim3(576), 0, stream>>>(weight, wbf);
  k_main<<<dim3(576), dim3(512), 0, stream>>>(incl, offset, mask, wbf, bias, out);
}